// Round 7
// baseline (201.998 us; speedup 1.0000x reference)
//
#include <hip/hip_runtime.h>

// B=4, S=1024, E=1024, H=16, D=64. All GEMMs are 4096x1024x1024 (A MxK row-major,
// W NxK row-major => C = A * W^T + bias).

typedef _Float16 v8h __attribute__((ext_vector_type(8)));
typedef _Float16 v4h __attribute__((ext_vector_type(4)));
typedef float    v4f __attribute__((ext_vector_type(4)));

#define MFMA_F16(A_, B_, C_) __builtin_amdgcn_mfma_f32_16x16x32_f16(A_, B_, C_, 0, 0, 0)

__device__ __forceinline__ void async_copy16(const void* g, void* l) {
    __builtin_amdgcn_global_load_lds(
        (const __attribute__((address_space(1))) void*)g,
        (__attribute__((address_space(3))) void*)l, 16, 0, 0);
}

// raw v_exp_f32 (2^x): avoids __expf's extra v_mul by log2e per element
__device__ __forceinline__ float exp2_hw(float x) {
#if __has_builtin(__builtin_amdgcn_exp2f)
    return __builtin_amdgcn_exp2f(x);
#else
    float r;
    asm("v_exp_f32 %0, %1" : "=v"(r) : "v"(x));
    return r;
#endif
}

// ---------------- fp32 -> fp16 conversion (5 tensors, one launch) ----------------
__global__ __launch_bounds__(256) void cvt5_kernel(
    const float* __restrict__ s0, const float* __restrict__ s1,
    const float* __restrict__ s2, const float* __restrict__ s3,
    const float* __restrict__ s4,
    _Float16* __restrict__ d0, _Float16* __restrict__ d1,
    _Float16* __restrict__ d2, _Float16* __restrict__ d3,
    _Float16* __restrict__ d4,
    int n0, int n1, int n2, int n3, int n4)
{
    const float* s; _Float16* d; int n;
    switch (blockIdx.y) {
        case 0:  s = s0; d = d0; n = n0; break;
        case 1:  s = s1; d = d1; n = n1; break;
        case 2:  s = s2; d = d2; n = n2; break;
        case 3:  s = s3; d = d3; n = n3; break;
        default: s = s4; d = d4; n = n4; break;
    }
    int i = (blockIdx.x * 256 + threadIdx.x) * 4;
    if (i >= n) return;
    float4 f = *(const float4*)(s + i);
    v4h o = { (_Float16)f.x, (_Float16)f.y, (_Float16)f.z, (_Float16)f.w };
    *(v4h*)(d + i) = o;
}

// ---------------- shared GEMM core: C = A * W^T + bias ----------------
// TM x 128 tile, BK=64, 256 threads (4 waves). Round-7: DOUBLE-BUFFERED staging
// (the old loop was sync;stage(kb);sync;compute(kb) — a full global-memory latency
// stall per K-iteration at only 2 blocks/CU). Now: prologue stages tile 0; each
// iteration stages kb+1 into the other buffer, computes kb, one barrier (the same
// verified pattern as the attn kernel's K/V pipeline). Hazards: buffer written in
// iter it was last read in iter it-1 (pre-barrier); end-of-iter barrier drains
// vmcnt so next iter may read it. LDS: TM=128 -> 64KB, TM=64 -> 48KB; both still
// >= the grid-limited 2 blocks/CU, so no occupancy loss.
// XOR-swizzled LDS (16B chunk c of row r holds logical chunk c ^ (r&7)); staged via
// global_load_lds 16B/lane. Epilogue via per-wave LDS scratch -> coalesced stores.
// MODE 0: fp16 (B,H,S,D).
// MODE 1: fp16 transposed (B,H,D,S) with PER-64-BLOCK k-permutation
//         p(k) = ((k>>2)&3)*8 + ((k>>4)&1)*4 + (k&3) + 32*(k>>5), so the attention
//         kernel's PV V-fragment is a contiguous conflict-free b128 read.
// MODE 2: fp32 (M,N), TM=64 (wave tile 64x32).
template<int TM, int MODE>
__device__ __forceinline__ void gemm_core(const _Float16* __restrict__ A,
                                          const _Float16* __restrict__ W,
                                          const float* __restrict__ bias,
                                          void* __restrict__ outp,
                                          int row0, int col0)
{
    constexpr int WCOLS = (TM == 128) ? 64 : 32;
    constexpr int NJ = WCOLS / 16;
    constexpr int SC_H = (MODE == 2) ? 4096 : 64 * WCOLS;  // per-wave scratch (halves)
    constexpr int STG_H = (TM + 128) * 64;                 // one staging buffer
    constexpr int TOT_H = (2 * STG_H > 4 * SC_H) ? 2 * STG_H : 4 * SC_H;
    __shared__ __align__(16) _Float16 smem[TOT_H];

    const int tid  = threadIdx.x;
    const int wave = tid >> 6, lane = tid & 63;
    const int quad = lane >> 4, n16 = lane & 15;
    const int wm = (TM == 128) ? (wave >> 1) : 0;
    const int wn = (TM == 128) ? (wave & 1) : wave;
    const int rL = lane >> 3, c8 = lane & 7;
    const int lcs = c8 ^ rL;

    v4f acc[4][NJ] = {};

    // stage K-tile kb into buffer b
    auto stage = [&](int kb, int b) {
        _Float16* Asb = smem + b * STG_H;
        _Float16* Bsb = Asb + TM * 64;
        #pragma unroll
        for (int p = 0; p < TM / 32; p++) {
            int rg = wave * (TM / 32) + p;
            int row = rg * 8 + rL;
            async_copy16(A + (size_t)(row0 + row) * 1024 + kb + lcs * 8, &Asb[rg * 512]);
        }
        #pragma unroll
        for (int p = 0; p < 4; p++) {
            int rg = wave * 4 + p;
            int row = rg * 8 + rL;
            async_copy16(W + (size_t)(col0 + row) * 1024 + kb + lcs * 8, &Bsb[rg * 512]);
        }
    };

    stage(0, 0);
    __syncthreads();                       // tile 0 resident

    for (int kb = 0; kb < 1024; kb += 64) {
        const int cb = (kb >> 6) & 1;
        if (kb + 64 < 1024) stage(kb + 64, cb ^ 1);   // prefetch next tile
        const _Float16* Asb = smem + cb * STG_H;
        const _Float16* Bsb = Asb + TM * 64;
        #pragma unroll
        for (int ks = 0; ks < 64; ks += 32) {
            const int pc = ((ks >> 3) + quad) ^ (n16 & 7);
            v8h af[4], bf[NJ];
            #pragma unroll
            for (int i = 0; i < 4; i++)
                af[i] = *(const v8h*)(&Asb[(wm * 64 + i * 16 + n16) * 64 + pc * 8]);
            #pragma unroll
            for (int j = 0; j < NJ; j++)
                bf[j] = *(const v8h*)(&Bsb[(wn * WCOLS + j * 16 + n16) * 64 + pc * 8]);
            #pragma unroll
            for (int i = 0; i < 4; i++)
                #pragma unroll
                for (int j = 0; j < NJ; j++)
                    acc[i][j] = MFMA_F16(af[i], bf[j], acc[i][j]);
        }
        __syncthreads();   // drains prefetch; frees buffer cb for tile kb+128
    }

    // loop-end barrier already separates the last tile's reads from scratch reuse
    const int b     = (row0 + wm * 64) >> 10;
    const int srow0 = (row0 + wm * 64) & 1023;
    const int C0    = col0 + wn * WCOLS;

    if (MODE == 0) {                       // [s][d] scratch, coalesced (B,H,S,D) stores
        _Float16* sc = smem + wave * SC_H;
        #pragma unroll
        for (int i = 0; i < 4; i++)
            #pragma unroll
            for (int j = 0; j < NJ; j++)
                #pragma unroll
                for (int r = 0; r < 4; r++) {
                    int rowL = i * 16 + quad * 4 + r, colL = j * 16 + n16;
                    float v = acc[i][j][r] + bias[C0 + colL];
                    sc[rowL * 64 + (((colL >> 3) ^ (rowL & 7)) << 3) + (colL & 7)] = (_Float16)v;
                }
        int h = C0 >> 6;
        #pragma unroll
        for (int it = 0; it < 8; it++) {
            int rowR = it * 8 + (lane >> 3), cR = lane & 7;
            v8h val = *(const v8h*)(&sc[rowR * 64 + ((cR ^ (rowR & 7)) << 3)]);
            *(v8h*)((_Float16*)outp +
                    (((size_t)(b * 16 + h) * 1024 + srow0 + rowR) << 6) + cR * 8) = val;
        }
    } else if (MODE == 1) {                // [d][s] scratch, permuted (B,H,D,S) stores
        _Float16* sc = smem + wave * SC_H;
        #pragma unroll
        for (int i = 0; i < 4; i++)
            #pragma unroll
            for (int j = 0; j < NJ; j++) {
                int colL = j * 16 + n16;
                int c16 = i * 2 + (quad >> 1);
                v4h pk;
                #pragma unroll
                for (int r = 0; r < 4; r++)
                    pk[r] = (_Float16)(acc[i][j][r] + bias[C0 + colL]);
                *(v4h*)(&sc[colL * 64 + ((c16 ^ (colL & 7)) << 3) + (quad & 1) * 4]) = pk;
            }
        #pragma unroll
        for (int it = 0; it < 8; it++) {
            int dR = it * 8 + (lane >> 3), g = lane & 7;
            v8h val = *(const v8h*)(&sc[dR * 64 + ((g ^ (dR & 7)) << 3)]);
            int cg = C0 + dR;
            int h = cg >> 6, dl = cg & 63;
            _Float16* base = (_Float16*)outp +
                             ((size_t)((b * 16 + h) * 64 + dl) << 10) + srow0;
            // k-block permutation: original s-cols [8g..8g+7] scatter as two v4h
            int a4  = ((g >> 1) & 1) * 4, b32 = (g >> 2) * 32;
            int p0  = b32 + ((2 * g) & 3) * 8 + a4;
            int p1  = b32 + ((2 * g + 1) & 3) * 8 + a4;
            v4h lo = __builtin_shufflevector(val, val, 0, 1, 2, 3);
            v4h hi = __builtin_shufflevector(val, val, 4, 5, 6, 7);
            *(v4h*)(base + p0) = lo;
            *(v4h*)(base + p1) = hi;
        }
    } else {                               // MODE 2 (TM=64): fp32 [m][n], wave tile 64x32
        float* sc = (float*)smem + wave * 2048;
        #pragma unroll
        for (int i = 0; i < 4; i++)
            #pragma unroll
            for (int j = 0; j < 2; j++)
                #pragma unroll
                for (int r = 0; r < 4; r++) {
                    int rowL = i * 16 + quad * 4 + r, colL = j * 16 + n16;
                    sc[rowL * 32 + (((colL >> 2) ^ (rowL & 7)) << 2) + (colL & 3)] =
                        acc[i][j][r] + bias[col0 + wn * 32 + colL];
                }
        #pragma unroll
        for (int it = 0; it < 8; it++) {
            int rowR = it * 8 + (lane >> 3), cR = lane & 7;
            v4f val = *(const v4f*)(&sc[rowR * 32 + ((cR ^ (rowR & 7)) << 2)]);
            *(v4f*)((float*)outp + (size_t)(row0 + rowR) * 1024 + col0 + wn * 32 + cR * 4) = val;
        }
    }
}

// 512 blocks, TM=128. XCD swizzle keyed on A row-strip.
__global__ __launch_bounds__(256) void gemm_qv_kernel(
    const _Float16* __restrict__ Aq, const _Float16* __restrict__ Av,
    const _Float16* __restrict__ Wq, const _Float16* __restrict__ Wv,
    const float* __restrict__ bq, const float* __restrict__ bv,
    _Float16* __restrict__ q_out, _Float16* __restrict__ v_out)
{
    int id = blockIdx.x;
    int y = (id & 7) | (((id >> 3) & 3) << 3);   // 0..31
    int x = (id >> 5) & 7;                       // 0..7
    int z = id >> 8;                             // 0..1
    if (z) gemm_core<128, 1>(Av, Wv, bv, (void*)v_out, y * 128, x * 128);
    else   gemm_core<128, 0>(Aq, Wq, bq, (void*)q_out, y * 128, x * 128);
}

// 512 blocks, TM=64, fp32 output.
__global__ __launch_bounds__(256) void gemm_o_kernel(
    const _Float16* __restrict__ A, const _Float16* __restrict__ W,
    const float* __restrict__ bias, float* __restrict__ outp)
{
    int id = blockIdx.x;
    int y = (id & 7) * 8 + ((id >> 3) & 7);      // 0..63
    int x = id >> 6;                             // 0..7
    gemm_core<64, 2>(A, W, bias, (void*)outp, y * 64, x * 128);
}

// ---------------- fused attention (S^T, static-max softmax, K == Q) -------------
// Block: 64 q-rows (4 waves x 16). 1-D grid: bh = blk&63 (XCD-local), qtile = blk>>6.
// Round-6 structure (kept): single barrier per k-iteration; V double-buffered in
// LDS with inline PV fragment reads; QK-ahead software pipeline (round-4, +12%);
// exp2-folded softmax; |dqt|>=17 fast paths; tree buckets; no setprio.
// Attn has plateaued at ~41 us across three schedules — remaining time is the
// serial chain at the grid-limited 4 waves/SIMD.
__global__ __launch_bounds__(256, 4) void attn_kernel(
    const _Float16* __restrict__ qb,   // (B,H,S,D) fp16
    const _Float16* __restrict__ vt,   // (B,H,D,S) fp16, k-permuted per 64-block
    const float* __restrict__ rpk, const float* __restrict__ rpv,  // (5,64) fp32
    _Float16* __restrict__ attn_o)     // (B*S, H*D) fp16
{
    const int blk = blockIdx.x;
    const int bh = blk & 63;
    const int q0 = (blk >> 6) * 64;
    const int tid = threadIdx.x;
    const int wave = tid >> 6, lane = tid & 63;
    const int quad = lane >> 4, n16 = lane & 15;
    const int qw = q0 + wave * 16;
    const _Float16* Qh = qb + (size_t)bh * 1024 * 64;
    const _Float16* Vh = vt + (size_t)bh * 64 * 1024;

    __shared__ __align__(16) _Float16 Ks[2][64 * 64];
    __shared__ __align__(16) _Float16 Vs[2][64 * 64];
    __shared__ float rqs[4][16][5];

    const int rL = lane >> 3, c8 = lane & 7;
    const int lcs = c8 ^ rL;

    // prologue: stage K[0]->Ks[0], K[1]->Ks[1], V[0]->Vs[0]
    #pragma unroll
    for (int p = 0; p < 2; p++) {
        int c = wave * 2 + p;
        int row = c * 8 + rL;
        async_copy16(Qh + (size_t)row * 64 + lcs * 8, &Ks[0][c * 512]);
        async_copy16(Qh + (size_t)(64 + row) * 64 + lcs * 8, &Ks[1][c * 512]);
        async_copy16(Vh + (size_t)row * 1024 + lcs * 8, &Vs[0][c * 512]);
    }

    // rc[t] = (dot(q_row, rpk[t]) - |q_row|^2) * 0.125 * log2e  (exp2-folded)
    {
        int m = lane >> 2, seg = lane & 3;
        const _Float16* qrow = Qh + (size_t)(qw + m) * 64 + seg * 16;
        v8h qa = *(const v8h*)(qrow);
        v8h qc = *(const v8h*)(qrow + 8);
        float qd[16];
        #pragma unroll
        for (int x = 0; x < 8; x++) { qd[x] = (float)qa[x]; qd[8 + x] = (float)qc[x]; }
        float qq = 0.f;
        #pragma unroll
        for (int x = 0; x < 16; x++) qq += qd[x] * qd[x];
        qq += __shfl_xor(qq, 1);
        qq += __shfl_xor(qq, 2);
        #pragma unroll
        for (int t = 0; t < 5; t++) {
            float s = 0.f;
            #pragma unroll
            for (int x = 0; x < 16; x++) s += qd[x] * rpk[t * 64 + seg * 16 + x];
            s += __shfl_xor(s, 1);
            s += __shfl_xor(s, 2);
            if (seg == 0) rqs[wave][m][t] = (s - qq) * 0.18033688736f;
        }
    }

    // Q fragment (B-operand): B[n=q=lane&15][k=quad*8+j]
    v8h aq0 = *(const v8h*)(Qh + (size_t)(qw + n16) * 64 + quad * 8);
    v8h aq1 = *(const v8h*)(Qh + (size_t)(qw + n16) * 64 + 32 + quad * 8);

    __syncthreads();   // K[0], K[1], V[0] resident; rqs visible

    float rc[5];
    #pragma unroll
    for (int t = 0; t < 5; t++) rc[t] = rqs[wave][n16][t];

    const int pphys0 = quad ^ (n16 & 7);
    const int pphys1 = (quad + 4) ^ (n16 & 7);
    const float SCL = 0.18033688736f;      // 0.125 * log2(e)

    // pipeline prime: s_cur = QK(K[0])
    v4f scur[4];
    #pragma unroll
    for (int t = 0; t < 4; t++) {
        v8h k0 = *(const v8h*)(&Ks[0][(t * 16 + n16) * 64 + pphys0 * 8]);
        v8h k1 = *(const v8h*)(&Ks[0][(t * 16 + n16) * 64 + pphys1 * 8]);
        v4f s = {0.f, 0.f, 0.f, 0.f};
        s = MFMA_F16(k0, aq0, s);
        scur[t] = MFMA_F16(k1, aq1, s);
    }
    __syncthreads();   // all waves done reading Ks[0] before iter 0 stages K[2] into it

    // bucket sums for this lane's q-row (index = rpk/rpv table row):
    // 4: diff>=2, 3: diff==1, 2: diff==0, 1: diff==-1, 0: diff<=-2
    float bkt[5] = {0.f, 0.f, 0.f, 0.f, 0.f};
    v4f O[4] = {};

    for (int it = 0; it < 16; ++it) {
        const int kb = it * 64;

        // 1. stage V[it+1] -> Vs[(it+1)&1] and K[it+2] -> Ks[it&1] (earliest issue)
        if (it + 1 < 16) {
            #pragma unroll
            for (int p = 0; p < 2; p++) {
                int c = wave * 2 + p;
                int row = c * 8 + rL;
                async_copy16(Vh + (size_t)row * 1024 + kb + 64 + lcs * 8,
                             &Vs[(it + 1) & 1][c * 512]);
            }
        }
        if (it + 2 < 16) {
            const int kn = kb + 128;
            #pragma unroll
            for (int p = 0; p < 2; p++) {
                int c = wave * 2 + p;
                int row = c * 8 + rL;
                async_copy16(Qh + (size_t)(kn + row) * 64 + lcs * 8, &Ks[it & 1][c * 512]);
            }
        }

        // 2. QK-ahead: s_next = QK(K[it+1]) from Ks[(it+1)&1] — independent of exp
        v4f snx[4] = {};
        if (it + 1 < 16) {
            #pragma unroll
            for (int t = 0; t < 4; t++) {
                v8h k0 = *(const v8h*)(&Ks[(it + 1) & 1][(t * 16 + n16) * 64 + pphys0 * 8]);
                v8h k1 = *(const v8h*)(&Ks[(it + 1) & 1][(t * 16 + n16) * 64 + pphys1 * 8]);
                v4f s = {0.f, 0.f, 0.f, 0.f};
                s = MFMA_F16(k0, aq0, s);
                snx[t] = MFMA_F16(k1, aq1, s);
            }
        }

        // 3. exp/pack on s_cur: lane owns q = qw+n16, k = t*16 + quad*4 + r
        int pkLo[4], pkHi[4];
        #pragma unroll
        for (int t = 0; t < 4; t++) {
            const v4f s = scur[t];
            const int dqt = qw - kb - t * 16;      // wave-uniform
            float pv[4];
            if (dqt >= 17) {                       // whole tile diff >= 2
                float p0 = exp2_hw(fmaf(s[0], SCL, rc[4]));
                float p1 = exp2_hw(fmaf(s[1], SCL, rc[4]));
                float p2 = exp2_hw(fmaf(s[2], SCL, rc[4]));
                float p3 = exp2_hw(fmaf(s[3], SCL, rc[4]));
                pv[0] = p0; pv[1] = p1; pv[2] = p2; pv[3] = p3;
                bkt[4] += (p0 + p1) + (p2 + p3);   // tree: short dep chain
            } else if (dqt <= -17) {               // whole tile diff <= -2
                float p0 = exp2_hw(fmaf(s[0], SCL, rc[0]));
                float p1 = exp2_hw(fmaf(s[1], SCL, rc[0]));
                float p2 = exp2_hw(fmaf(s[2], SCL, rc[0]));
                float p3 = exp2_hw(fmaf(s[3], SCL, rc[0]));
                pv[0] = p0; pv[1] = p1; pv[2] = p2; pv[3] = p3;
                bkt[0] += (p0 + p1) + (p2 + p3);
            } else {                               // near-diagonal tile
                const int D0 = dqt + n16 - quad * 4;
                #pragma unroll
                for (int r = 0; r < 4; r++) {
                    int diff = D0 - r;
                    float rv = diff >= 2  ? rc[4]
                             : diff == 1  ? rc[3]
                             : diff == 0  ? rc[2]
                             : diff == -1 ? rc[1]
                                          : rc[0];
                    float p = exp2_hw(fmaf(s[r], SCL, rv));
                    pv[r] = p;
                    bkt[4] += (diff >= 2)  ? p : 0.f;
                    bkt[3] += (diff == 1)  ? p : 0.f;
                    bkt[2] += (diff == 0)  ? p : 0.f;
                    bkt[1] += (diff == -1) ? p : 0.f;
                    bkt[0] += (diff <= -2) ? p : 0.f;
                }
            }
            pkLo[t] = __builtin_bit_cast(int, __builtin_amdgcn_cvt_pkrtz(pv[0], pv[1]));
            pkHi[t] = __builtin_bit_cast(int, __builtin_amdgcn_cvt_pkrtz(pv[2], pv[3]));
        }

        // 4. PV from Vs[it&1] (staged last iter, already drained): V fragments are
        //    read inline — short-lived registers, no spill pressure.
        union { int d[4]; v8h v; } ub0, ub1;
        ub0.d[0] = pkLo[0]; ub0.d[1] = pkHi[0]; ub0.d[2] = pkLo[1]; ub0.d[3] = pkHi[1];
        ub1.d[0] = pkLo[2]; ub1.d[1] = pkHi[2]; ub1.d[2] = pkLo[3]; ub1.d[3] = pkHi[3];
        v8h bf0 = ub0.v, bf1 = ub1.v;

        #pragma unroll
        for (int dt = 0; dt < 4; dt++) {
            const int rowd = (dt * 16 + n16) * 64;
            v8h av0 = *(const v8h*)(&Vs[it & 1][rowd + pphys0 * 8]);
            v8h av1 = *(const v8h*)(&Vs[it & 1][rowd + pphys1 * 8]);
            O[dt] = MFMA_F16(av0, bf0, O[dt]);    // O^T: row = d-local, col = q
            O[dt] = MFMA_F16(av1, bf1, O[dt]);
        }

        // 5. single barrier: drains V[it+1]/K[it+2] staging; rendezvous frees
        //    Vs[it&1] and Ks[(it+1)&1] for next iter's staging.
        __syncthreads();

        // rotate pipeline registers
        #pragma unroll
        for (int t = 0; t < 4; t++) scur[t] = snx[t];
    }

    // epilogue: reduce buckets across the 4 quads sharing this q-row
    #pragma unroll
    for (int t = 0; t < 5; t++) {
        bkt[t] += __shfl_xor(bkt[t], 16);
        bkt[t] += __shfl_xor(bkt[t], 32);
    }
    float l = bkt[0] + bkt[1] + bkt[2] + bkt[3] + bkt[4];
    float inv = 1.0f / l;
    int q = qw + n16;
    size_t orow = (size_t)((bh >> 4) * 1024 + q) * 1024 + (bh & 15) * 64;
    #pragma unroll
    for (int dt = 0; dt < 4; dt++) {
        int d0 = dt * 16 + quad * 4;
        v4h st;
        #pragma unroll
        for (int r = 0; r < 4; r++) {
            int d = d0 + r;
            float w2 = bkt[4] * rpv[4 * 64 + d] + bkt[3] * rpv[3 * 64 + d]
                     + bkt[2] * rpv[2 * 64 + d] + bkt[1] * rpv[1 * 64 + d]
                     + bkt[0] * rpv[0 * 64 + d];
            st[r] = (_Float16)((O[dt][r] + w2) * inv);
        }
        *(v4h*)(attn_o + orow + d0) = st;
    }
}

// ---------------- host launcher ----------------
extern "C" void kernel_launch(void* const* d_in, const int* in_sizes, int n_in,
                              void* d_out, int out_size, void* d_ws, size_t ws_size,
                              hipStream_t stream)
{
    const float* query = (const float*)d_in[0];
    // d_in[1] = key (unused: reference's k projection is dead code)
    const float* value = (const float*)d_in[2];
    const float* Wq = (const float*)d_in[3];
    const float* bq = (const float*)d_in[4];
    // d_in[5], d_in[6] = Wk, bk (unused)
    const float* Wv = (const float*)d_in[7];
    const float* bv = (const float*)d_in[8];
    const float* Wo = (const float*)d_in[9];
    const float* bo = (const float*)d_in[10];
    const float* rpk = (const float*)d_in[11];
    const float* rpv = (const float*)d_in[12];
    float* out = (float*)d_out;

    char* ws = (char*)d_ws;
    const size_t MB = 1024 * 1024;
    _Float16* q_bhsd = (_Float16*)(ws);             // 8 MB: q proj (B,H,S,D)
    _Float16* v_t    = (_Float16*)(ws + 8 * MB);    // 8 MB: v proj (B,H,D,S) permuted
    _Float16* q16    = (_Float16*)(ws + 16 * MB);   // 8 MB: query fp16
    _Float16* attn_o = (_Float16*)(ws + 16 * MB);   // aliases q16 (dead after gemm_qv)
    _Float16* v16    = (_Float16*)(ws + 24 * MB);   // 8 MB: value fp16
    _Float16* wq16   = (_Float16*)(ws + 32 * MB);   // 2 MB
    _Float16* wv16   = (_Float16*)(ws + 34 * MB);   // 2 MB
    _Float16* wo16   = (_Float16*)(ws + 36 * MB);   // 2 MB   (total 38 MB)

    cvt5_kernel<<<dim3(4096, 5), 256, 0, stream>>>(
        query, value, Wq, Wv, Wo, q16, v16, wq16, wv16, wo16,
        4096 * 1024, 4096 * 1024, 1024 * 1024, 1024 * 1024, 1024 * 1024);

    gemm_qv_kernel<<<dim3(512), 256, 0, stream>>>(
        q16, v16, wq16, wv16, bq, bv, q_bhsd, v_t);

    attn_kernel<<<dim3(1024), 256, 0, stream>>>(q_bhsd, v_t, rpk, rpv, attn_o);

    gemm_o_kernel<<<dim3(512), 256, 0, stream>>>(attn_o, wo16, bo, out);
}

// Round 8
// 199.959 us; speedup vs baseline: 1.0102x; 1.0102x over previous
//
#include <hip/hip_runtime.h>

// B=4, S=1024, E=1024, H=16, D=64. All GEMMs are 4096x1024x1024 (A MxK row-major,
// W NxK row-major => C = A * W^T + bias).

typedef _Float16 v8h __attribute__((ext_vector_type(8)));
typedef _Float16 v4h __attribute__((ext_vector_type(4)));
typedef float    v4f __attribute__((ext_vector_type(4)));

#define MFMA_F16(A_, B_, C_) __builtin_amdgcn_mfma_f32_16x16x32_f16(A_, B_, C_, 0, 0, 0)

__device__ __forceinline__ void async_copy16(const void* g, void* l) {
    __builtin_amdgcn_global_load_lds(
        (const __attribute__((address_space(1))) void*)g,
        (__attribute__((address_space(3))) void*)l, 16, 0, 0);
}

// raw v_exp_f32 (2^x): avoids __expf's extra v_mul by log2e per element
__device__ __forceinline__ float exp2_hw(float x) {
#if __has_builtin(__builtin_amdgcn_exp2f)
    return __builtin_amdgcn_exp2f(x);
#else
    float r;
    asm("v_exp_f32 %0, %1" : "=v"(r) : "v"(x));
    return r;
#endif
}

// ---------------- fp32 -> fp16 conversion (5 tensors, one launch) ----------------
__global__ __launch_bounds__(256) void cvt5_kernel(
    const float* __restrict__ s0, const float* __restrict__ s1,
    const float* __restrict__ s2, const float* __restrict__ s3,
    const float* __restrict__ s4,
    _Float16* __restrict__ d0, _Float16* __restrict__ d1,
    _Float16* __restrict__ d2, _Float16* __restrict__ d3,
    _Float16* __restrict__ d4,
    int n0, int n1, int n2, int n3, int n4)
{
    const float* s; _Float16* d; int n;
    switch (blockIdx.y) {
        case 0:  s = s0; d = d0; n = n0; break;
        case 1:  s = s1; d = d1; n = n1; break;
        case 2:  s = s2; d = d2; n = n2; break;
        case 3:  s = s3; d = d3; n = n3; break;
        default: s = s4; d = d4; n = n4; break;
    }
    int i = (blockIdx.x * 256 + threadIdx.x) * 4;
    if (i >= n) return;
    float4 f = *(const float4*)(s + i);
    v4h o = { (_Float16)f.x, (_Float16)f.y, (_Float16)f.z, (_Float16)f.w };
    *(v4h*)(d + i) = o;
}

// ---------------- shared GEMM core: C = A * W^T + bias ----------------
// Round-8: tile TM x TN with TN=64 (was 128) so grids double to 1024 blocks =
// 4 blocks/CU = 4 waves/SIMD (was 2 — the GEMMs were occupancy/latency-starved
// exactly like the attn kernel before its fixes). Single-buffer staging (round-7
// dbuf reverted: no gain, 2x LDS). Waves arranged 2x2; wave tile (TM/2)x(TN/2).
// LDS: qv 24KB, o 16KB -> 4 blocks/CU (thread-capped) fit comfortably.
// XOR-swizzled LDS staging via global_load_lds 16B/lane (16B chunk c of row r
// holds logical chunk c ^ (r&7)).
// Epilogue: block-global scratch (reusing staging LDS) + cooperative coalesced
// stores; TN=64 aligns each tile to exactly one head for MODE 0/1.
// MODE 0: fp16 out (B,H,S,D).
// MODE 1: fp16 out transposed (B,H,D,S) with PER-64-BLOCK k-permutation
//         p(k) = ((k>>2)&3)*8 + ((k>>4)&1)*4 + (k&3) + 32*(k>>5), so the attention
//         kernel's PV V-fragment is a contiguous conflict-free b128 read.
// MODE 2: fp32 out (M,N), TM=64.
template<int TM, int TN, int MODE>
__device__ __forceinline__ void gemm_core(const _Float16* __restrict__ A,
                                          const _Float16* __restrict__ W,
                                          const float* __restrict__ bias,
                                          void* __restrict__ outp,
                                          int row0, int col0)
{
    constexpr int WROWS = TM / 2, WCOLS = TN / 2;
    constexpr int MI = WROWS / 16, NJ = WCOLS / 16;
    constexpr int STG_H = (TM + TN) * 64;
    constexpr int SCR_H = (MODE == 2) ? TM * TN * 2 : TM * TN;   // halves
    constexpr int TOT_H = (STG_H > SCR_H) ? STG_H : SCR_H;
    __shared__ __align__(16) _Float16 smem[TOT_H];
    _Float16* As = smem;
    _Float16* Bs = smem + TM * 64;

    const int tid  = threadIdx.x;
    const int wave = tid >> 6, lane = tid & 63;
    const int quad = lane >> 4, n16 = lane & 15;
    const int wm = wave >> 1, wn = wave & 1;
    const int rL = lane >> 3, c8 = lane & 7;
    const int lcs = c8 ^ rL;

    v4f acc[MI][NJ] = {};

    for (int kb = 0; kb < 1024; kb += 64) {
        __syncthreads();
        #pragma unroll
        for (int p = 0; p < TM / 32; p++) {
            int rg = wave * (TM / 32) + p;
            int row = rg * 8 + rL;
            async_copy16(A + (size_t)(row0 + row) * 1024 + kb + lcs * 8, &As[rg * 512]);
        }
        #pragma unroll
        for (int p = 0; p < TN / 32; p++) {
            int rg = wave * (TN / 32) + p;
            int row = rg * 8 + rL;
            async_copy16(W + (size_t)(col0 + row) * 1024 + kb + lcs * 8, &Bs[rg * 512]);
        }
        __syncthreads();
        #pragma unroll
        for (int ks = 0; ks < 64; ks += 32) {
            const int pc = ((ks >> 3) + quad) ^ (n16 & 7);
            v8h af[MI], bf[NJ];
            #pragma unroll
            for (int i = 0; i < MI; i++)
                af[i] = *(const v8h*)(&As[(wm * WROWS + i * 16 + n16) * 64 + pc * 8]);
            #pragma unroll
            for (int j = 0; j < NJ; j++)
                bf[j] = *(const v8h*)(&Bs[(wn * WCOLS + j * 16 + n16) * 64 + pc * 8]);
            #pragma unroll
            for (int i = 0; i < MI; i++)
                #pragma unroll
                for (int j = 0; j < NJ; j++)
                    acc[i][j] = MFMA_F16(af[i], bf[j], acc[i][j]);
        }
    }

    __syncthreads();                       // staged tiles dead; reuse LDS as scratch
    const int b     = row0 >> 10;
    const int srow0 = row0 & 1023;
    const int h     = col0 >> 6;           // TN=64: tile = exactly one head (MODE 0/1)

    if (MODE == 0) {                       // scratch [TM][64] halves, swizzled rows
        _Float16* sc = smem;
        #pragma unroll
        for (int i = 0; i < MI; i++)
            #pragma unroll
            for (int j = 0; j < NJ; j++)
                #pragma unroll
                for (int r = 0; r < 4; r++) {
                    int rowL = wm * WROWS + i * 16 + quad * 4 + r;
                    int colL = wn * WCOLS + j * 16 + n16;
                    float v = acc[i][j][r] + bias[col0 + colL];
                    sc[rowL * 64 + (((colL >> 3) ^ (rowL & 7)) << 3) + (colL & 7)] = (_Float16)v;
                }
        __syncthreads();
        #pragma unroll
        for (int it = 0; it < TM / 32; it++) {
            int rowR = it * 32 + (tid >> 3), cR = tid & 7;
            v8h val = *(const v8h*)(&sc[rowR * 64 + ((cR ^ (rowR & 7)) << 3)]);
            *(v8h*)((_Float16*)outp +
                    (((size_t)(b * 16 + h) * 1024 + srow0 + rowR) << 6) + cR * 8) = val;
        }
    } else if (MODE == 1) {                // scratch [64 d][TM s] halves, swizzled
        _Float16* sc = smem;
        #pragma unroll
        for (int i = 0; i < MI; i++)
            #pragma unroll
            for (int j = 0; j < NJ; j++) {
                int colL = wn * WCOLS + j * 16 + n16;       // d
                int s0   = wm * WROWS + i * 16 + quad * 4;  // s (4 consecutive)
                v4h pk;
                #pragma unroll
                for (int r = 0; r < 4; r++)
                    pk[r] = (_Float16)(acc[i][j][r] + bias[col0 + colL]);
                *(v4h*)(&sc[colL * TM + (((s0 >> 3) ^ (colL & 7)) << 3) + (s0 & 7)]) = pk;
            }
        __syncthreads();
        #pragma unroll
        for (int it = 0; it < 4; it++) {
            int dR = it * 16 + (tid >> 4);                  // 0..63
            int g  = tid & 15;                              // s-chunk (8 halves)
            v8h val = *(const v8h*)(&sc[dR * TM + ((g ^ (dR & 7)) << 3)]);
            int s64 = g >> 3, gs = g & 7;
            _Float16* base = (_Float16*)outp +
                             ((size_t)((b * 16 + h) * 64 + dR) << 10) + srow0 + s64 * 64;
            // k-block permutation: logical s-cols [8gs..8gs+7] scatter as two v4h
            int a4  = ((gs >> 1) & 1) * 4, b32 = (gs >> 2) * 32;
            int p0  = b32 + ((2 * gs) & 3) * 8 + a4;
            int p1  = b32 + ((2 * gs + 1) & 3) * 8 + a4;
            v4h lo = __builtin_shufflevector(val, val, 0, 1, 2, 3);
            v4h hi = __builtin_shufflevector(val, val, 4, 5, 6, 7);
            *(v4h*)(base + p0) = lo;
            *(v4h*)(base + p1) = hi;
        }
    } else {                               // MODE 2: scratch [TM][64] fp32, swizzled
        float* sc = (float*)smem;
        #pragma unroll
        for (int i = 0; i < MI; i++)
            #pragma unroll
            for (int j = 0; j < NJ; j++)
                #pragma unroll
                for (int r = 0; r < 4; r++) {
                    int rowL = wm * WROWS + i * 16 + quad * 4 + r;
                    int colL = wn * WCOLS + j * 16 + n16;
                    sc[rowL * 64 + (((colL >> 2) ^ (rowL & 7)) << 2) + (colL & 3)] =
                        acc[i][j][r] + bias[col0 + colL];
                }
        __syncthreads();
        #pragma unroll
        for (int it = 0; it < TM / 16; it++) {
            int rowR = it * 16 + (tid >> 4), cR = tid & 15;
            v4f val = *(const v4f*)(&sc[rowR * 64 + ((cR ^ (rowR & 7)) << 2)]);
            *(v4f*)((float*)outp + (size_t)(row0 + rowR) * 1024 + col0 + cR * 4) = val;
        }
    }
}

// 1024 blocks (4/CU), tile 128x64. XCD swizzle keyed on A row-strip.
__global__ __launch_bounds__(256) void gemm_qv_kernel(
    const _Float16* __restrict__ Aq, const _Float16* __restrict__ Av,
    const _Float16* __restrict__ Wq, const _Float16* __restrict__ Wv,
    const float* __restrict__ bq, const float* __restrict__ bv,
    _Float16* __restrict__ q_out, _Float16* __restrict__ v_out)
{
    int id = blockIdx.x;
    int z = id >> 9;                             // 0..1 (q / v)
    int r = id & 511;
    int y = (r & 7) | (((r >> 3) & 3) << 3);     // 0..31
    int x = (r >> 5) & 15;                       // 0..15
    if (z) gemm_core<128, 64, 1>(Av, Wv, bv, (void*)v_out, y * 128, x * 64);
    else   gemm_core<128, 64, 0>(Aq, Wq, bq, (void*)q_out, y * 128, x * 64);
}

// 1024 blocks (4/CU), tile 64x64, fp32 output.
__global__ __launch_bounds__(256) void gemm_o_kernel(
    const _Float16* __restrict__ A, const _Float16* __restrict__ W,
    const float* __restrict__ bias, float* __restrict__ outp)
{
    int id = blockIdx.x;
    int y = (id & 7) | (((id >> 3) & 7) << 3);   // 0..63
    int x = id >> 6;                             // 0..15
    gemm_core<64, 64, 2>(A, W, bias, (void*)outp, y * 64, x * 64);
}

// ---------------- fused attention (S^T, static-max softmax, K == Q) -------------
// Block: 64 q-rows (4 waves x 16). 1-D grid: bh = blk&63 (XCD-local), qtile = blk>>6.
// Round-6 structure (kept, verified 41.3us): single barrier per k-iteration; V
// double-buffered in LDS with inline PV fragment reads; QK-ahead software pipeline
// (round-4, +12%); exp2-folded softmax; |dqt|>=17 fast paths; tree buckets.
__global__ __launch_bounds__(256, 4) void attn_kernel(
    const _Float16* __restrict__ qb,   // (B,H,S,D) fp16
    const _Float16* __restrict__ vt,   // (B,H,D,S) fp16, k-permuted per 64-block
    const float* __restrict__ rpk, const float* __restrict__ rpv,  // (5,64) fp32
    _Float16* __restrict__ attn_o)     // (B*S, H*D) fp16
{
    const int blk = blockIdx.x;
    const int bh = blk & 63;
    const int q0 = (blk >> 6) * 64;
    const int tid = threadIdx.x;
    const int wave = tid >> 6, lane = tid & 63;
    const int quad = lane >> 4, n16 = lane & 15;
    const int qw = q0 + wave * 16;
    const _Float16* Qh = qb + (size_t)bh * 1024 * 64;
    const _Float16* Vh = vt + (size_t)bh * 64 * 1024;

    __shared__ __align__(16) _Float16 Ks[2][64 * 64];
    __shared__ __align__(16) _Float16 Vs[2][64 * 64];
    __shared__ float rqs[4][16][5];

    const int rL = lane >> 3, c8 = lane & 7;
    const int lcs = c8 ^ rL;

    // prologue: stage K[0]->Ks[0], K[1]->Ks[1], V[0]->Vs[0]
    #pragma unroll
    for (int p = 0; p < 2; p++) {
        int c = wave * 2 + p;
        int row = c * 8 + rL;
        async_copy16(Qh + (size_t)row * 64 + lcs * 8, &Ks[0][c * 512]);
        async_copy16(Qh + (size_t)(64 + row) * 64 + lcs * 8, &Ks[1][c * 512]);
        async_copy16(Vh + (size_t)row * 1024 + lcs * 8, &Vs[0][c * 512]);
    }

    // rc[t] = (dot(q_row, rpk[t]) - |q_row|^2) * 0.125 * log2e  (exp2-folded)
    {
        int m = lane >> 2, seg = lane & 3;
        const _Float16* qrow = Qh + (size_t)(qw + m) * 64 + seg * 16;
        v8h qa = *(const v8h*)(qrow);
        v8h qc = *(const v8h*)(qrow + 8);
        float qd[16];
        #pragma unroll
        for (int x = 0; x < 8; x++) { qd[x] = (float)qa[x]; qd[8 + x] = (float)qc[x]; }
        float qq = 0.f;
        #pragma unroll
        for (int x = 0; x < 16; x++) qq += qd[x] * qd[x];
        qq += __shfl_xor(qq, 1);
        qq += __shfl_xor(qq, 2);
        #pragma unroll
        for (int t = 0; t < 5; t++) {
            float s = 0.f;
            #pragma unroll
            for (int x = 0; x < 16; x++) s += qd[x] * rpk[t * 64 + seg * 16 + x];
            s += __shfl_xor(s, 1);
            s += __shfl_xor(s, 2);
            if (seg == 0) rqs[wave][m][t] = (s - qq) * 0.18033688736f;
        }
    }

    // Q fragment (B-operand): B[n=q=lane&15][k=quad*8+j]
    v8h aq0 = *(const v8h*)(Qh + (size_t)(qw + n16) * 64 + quad * 8);
    v8h aq1 = *(const v8h*)(Qh + (size_t)(qw + n16) * 64 + 32 + quad * 8);

    __syncthreads();   // K[0], K[1], V[0] resident; rqs visible

    float rc[5];
    #pragma unroll
    for (int t = 0; t < 5; t++) rc[t] = rqs[wave][n16][t];

    const int pphys0 = quad ^ (n16 & 7);
    const int pphys1 = (quad + 4) ^ (n16 & 7);
    const float SCL = 0.18033688736f;      // 0.125 * log2(e)

    // pipeline prime: s_cur = QK(K[0])
    v4f scur[4];
    #pragma unroll
    for (int t = 0; t < 4; t++) {
        v8h k0 = *(const v8h*)(&Ks[0][(t * 16 + n16) * 64 + pphys0 * 8]);
        v8h k1 = *(const v8h*)(&Ks[0][(t * 16 + n16) * 64 + pphys1 * 8]);
        v4f s = {0.f, 0.f, 0.f, 0.f};
        s = MFMA_F16(k0, aq0, s);
        scur[t] = MFMA_F16(k1, aq1, s);
    }
    __syncthreads();   // all waves done reading Ks[0] before iter 0 stages K[2] into it

    // bucket sums for this lane's q-row (index = rpk/rpv table row):
    // 4: diff>=2, 3: diff==1, 2: diff==0, 1: diff==-1, 0: diff<=-2
    float bkt[5] = {0.f, 0.f, 0.f, 0.f, 0.f};
    v4f O[4] = {};

    for (int it = 0; it < 16; ++it) {
        const int kb = it * 64;

        // 1. stage V[it+1] -> Vs[(it+1)&1] and K[it+2] -> Ks[it&1] (earliest issue)
        if (it + 1 < 16) {
            #pragma unroll
            for (int p = 0; p < 2; p++) {
                int c = wave * 2 + p;
                int row = c * 8 + rL;
                async_copy16(Vh + (size_t)row * 1024 + kb + 64 + lcs * 8,
                             &Vs[(it + 1) & 1][c * 512]);
            }
        }
        if (it + 2 < 16) {
            const int kn = kb + 128;
            #pragma unroll
            for (int p = 0; p < 2; p++) {
                int c = wave * 2 + p;
                int row = c * 8 + rL;
                async_copy16(Qh + (size_t)(kn + row) * 64 + lcs * 8, &Ks[it & 1][c * 512]);
            }
        }

        // 2. QK-ahead: s_next = QK(K[it+1]) from Ks[(it+1)&1] — independent of exp
        v4f snx[4] = {};
        if (it + 1 < 16) {
            #pragma unroll
            for (int t = 0; t < 4; t++) {
                v8h k0 = *(const v8h*)(&Ks[(it + 1) & 1][(t * 16 + n16) * 64 + pphys0 * 8]);
                v8h k1 = *(const v8h*)(&Ks[(it + 1) & 1][(t * 16 + n16) * 64 + pphys1 * 8]);
                v4f s = {0.f, 0.f, 0.f, 0.f};
                s = MFMA_F16(k0, aq0, s);
                snx[t] = MFMA_F16(k1, aq1, s);
            }
        }

        // 3. exp/pack on s_cur: lane owns q = qw+n16, k = t*16 + quad*4 + r
        int pkLo[4], pkHi[4];
        #pragma unroll
        for (int t = 0; t < 4; t++) {
            const v4f s = scur[t];
            const int dqt = qw - kb - t * 16;      // wave-uniform
            float pv[4];
            if (dqt >= 17) {                       // whole tile diff >= 2
                float p0 = exp2_hw(fmaf(s[0], SCL, rc[4]));
                float p1 = exp2_hw(fmaf(s[1], SCL, rc[4]));
                float p2 = exp2_hw(fmaf(s[2], SCL, rc[4]));
                float p3 = exp2_hw(fmaf(s[3], SCL, rc[4]));
                pv[0] = p0; pv[1] = p1; pv[2] = p2; pv[3] = p3;
                bkt[4] += (p0 + p1) + (p2 + p3);   // tree: short dep chain
            } else if (dqt <= -17) {               // whole tile diff <= -2
                float p0 = exp2_hw(fmaf(s[0], SCL, rc[0]));
                float p1 = exp2_hw(fmaf(s[1], SCL, rc[0]));
                float p2 = exp2_hw(fmaf(s[2], SCL, rc[0]));
                float p3 = exp2_hw(fmaf(s[3], SCL, rc[0]));
                pv[0] = p0; pv[1] = p1; pv[2] = p2; pv[3] = p3;
                bkt[0] += (p0 + p1) + (p2 + p3);
            } else {                               // near-diagonal tile
                const int D0 = dqt + n16 - quad * 4;
                #pragma unroll
                for (int r = 0; r < 4; r++) {
                    int diff = D0 - r;
                    float rv = diff >= 2  ? rc[4]
                             : diff == 1  ? rc[3]
                             : diff == 0  ? rc[2]
                             : diff == -1 ? rc[1]
                                          : rc[0];
                    float p = exp2_hw(fmaf(s[r], SCL, rv));
                    pv[r] = p;
                    bkt[4] += (diff >= 2)  ? p : 0.f;
                    bkt[3] += (diff == 1)  ? p : 0.f;
                    bkt[2] += (diff == 0)  ? p : 0.f;
                    bkt[1] += (diff == -1) ? p : 0.f;
                    bkt[0] += (diff <= -2) ? p : 0.f;
                }
            }
            pkLo[t] = __builtin_bit_cast(int, __builtin_amdgcn_cvt_pkrtz(pv[0], pv[1]));
            pkHi[t] = __builtin_bit_cast(int, __builtin_amdgcn_cvt_pkrtz(pv[2], pv[3]));
        }

        // 4. PV from Vs[it&1] (staged last iter, already drained): V fragments are
        //    read inline — short-lived registers, no spill pressure.
        union { int d[4]; v8h v; } ub0, ub1;
        ub0.d[0] = pkLo[0]; ub0.d[1] = pkHi[0]; ub0.d[2] = pkLo[1]; ub0.d[3] = pkHi[1];
        ub1.d[0] = pkLo[2]; ub1.d[1] = pkHi[2]; ub1.d[2] = pkLo[3]; ub1.d[3] = pkHi[3];
        v8h bf0 = ub0.v, bf1 = ub1.v;

        #pragma unroll
        for (int dt = 0; dt < 4; dt++) {
            const int rowd = (dt * 16 + n16) * 64;
            v8h av0 = *(const v8h*)(&Vs[it & 1][rowd + pphys0 * 8]);
            v8h av1 = *(const v8h*)(&Vs[it & 1][rowd + pphys1 * 8]);
            O[dt] = MFMA_F16(av0, bf0, O[dt]);    // O^T: row = d-local, col = q
            O[dt] = MFMA_F16(av1, bf1, O[dt]);
        }

        // 5. single barrier: drains V[it+1]/K[it+2] staging; rendezvous frees
        //    Vs[it&1] and Ks[(it+1)&1] for next iter's staging.
        __syncthreads();

        // rotate pipeline registers
        #pragma unroll
        for (int t = 0; t < 4; t++) scur[t] = snx[t];
    }

    // epilogue: reduce buckets across the 4 quads sharing this q-row
    #pragma unroll
    for (int t = 0; t < 5; t++) {
        bkt[t] += __shfl_xor(bkt[t], 16);
        bkt[t] += __shfl_xor(bkt[t], 32);
    }
    float l = bkt[0] + bkt[1] + bkt[2] + bkt[3] + bkt[4];
    float inv = 1.0f / l;
    int q = qw + n16;
    size_t orow = (size_t)((bh >> 4) * 1024 + q) * 1024 + (bh & 15) * 64;
    #pragma unroll
    for (int dt = 0; dt < 4; dt++) {
        int d0 = dt * 16 + quad * 4;
        v4h st;
        #pragma unroll
        for (int r = 0; r < 4; r++) {
            int d = d0 + r;
            float w2 = bkt[4] * rpv[4 * 64 + d] + bkt[3] * rpv[3 * 64 + d]
                     + bkt[2] * rpv[2 * 64 + d] + bkt[1] * rpv[1 * 64 + d]
                     + bkt[0] * rpv[0 * 64 + d];
            st[r] = (_Float16)((O[dt][r] + w2) * inv);
        }
        *(v4h*)(attn_o + orow + d0) = st;
    }
}

// ---------------- host launcher ----------------
extern "C" void kernel_launch(void* const* d_in, const int* in_sizes, int n_in,
                              void* d_out, int out_size, void* d_ws, size_t ws_size,
                              hipStream_t stream)
{
    const float* query = (const float*)d_in[0];
    // d_in[1] = key (unused: reference's k projection is dead code)
    const float* value = (const float*)d_in[2];
    const float* Wq = (const float*)d_in[3];
    const float* bq = (const float*)d_in[4];
    // d_in[5], d_in[6] = Wk, bk (unused)
    const float* Wv = (const float*)d_in[7];
    const float* bv = (const float*)d_in[8];
    const float* Wo = (const float*)d_in[9];
    const float* bo = (const float*)d_in[10];
    const float* rpk = (const float*)d_in[11];
    const float* rpv = (const float*)d_in[12];
    float* out = (float*)d_out;

    char* ws = (char*)d_ws;
    const size_t MB = 1024 * 1024;
    _Float16* q_bhsd = (_Float16*)(ws);             // 8 MB: q proj (B,H,S,D)
    _Float16* v_t    = (_Float16*)(ws + 8 * MB);    // 8 MB: v proj (B,H,D,S) permuted
    _Float16* q16    = (_Float16*)(ws + 16 * MB);   // 8 MB: query fp16
    _Float16* attn_o = (_Float16*)(ws + 16 * MB);   // aliases q16 (dead after gemm_qv)
    _Float16* v16    = (_Float16*)(ws + 24 * MB);   // 8 MB: value fp16
    _Float16* wq16   = (_Float16*)(ws + 32 * MB);   // 2 MB
    _Float16* wv16   = (_Float16*)(ws + 34 * MB);   // 2 MB
    _Float16* wo16   = (_Float16*)(ws + 36 * MB);   // 2 MB   (total 38 MB)

    cvt5_kernel<<<dim3(4096, 5), 256, 0, stream>>>(
        query, value, Wq, Wv, Wo, q16, v16, wq16, wv16, wo16,
        4096 * 1024, 4096 * 1024, 1024 * 1024, 1024 * 1024, 1024 * 1024);

    gemm_qv_kernel<<<dim3(1024), 256, 0, stream>>>(
        q16, v16, wq16, wv16, bq, bv, q_bhsd, v_t);

    attn_kernel<<<dim3(1024), 256, 0, stream>>>(q_bhsd, v_t, rpk, rpv, attn_o);

    gemm_o_kernel<<<dim3(1024), 256, 0, stream>>>(attn_o, wo16, bo, out);
}

// Round 9
// 190.639 us; speedup vs baseline: 1.0596x; 1.0489x over previous
//
#include <hip/hip_runtime.h>

// B=4, S=1024, E=1024, H=16, D=64. All GEMMs are 4096x1024x1024 (A MxK row-major,
// W NxK row-major => C = A * W^T + bias).

typedef _Float16 v8h __attribute__((ext_vector_type(8)));
typedef _Float16 v4h __attribute__((ext_vector_type(4)));
typedef float    v4f __attribute__((ext_vector_type(4)));

#define MFMA_F16(A_, B_, C_) __builtin_amdgcn_mfma_f32_16x16x32_f16(A_, B_, C_, 0, 0, 0)

__device__ __forceinline__ void async_copy16(const void* g, void* l) {
    __builtin_amdgcn_global_load_lds(
        (const __attribute__((address_space(1))) void*)g,
        (__attribute__((address_space(3))) void*)l, 16, 0, 0);
}

// raw v_exp_f32 (2^x): avoids __expf's extra v_mul by log2e per element
__device__ __forceinline__ float exp2_hw(float x) {
#if __has_builtin(__builtin_amdgcn_exp2f)
    return __builtin_amdgcn_exp2f(x);
#else
    float r;
    asm("v_exp_f32 %0, %1" : "=v"(r) : "v"(x));
    return r;
#endif
}

// ---------------- fp32 -> fp16 conversion (5 tensors, one launch) ----------------
__global__ __launch_bounds__(256) void cvt5_kernel(
    const float* __restrict__ s0, const float* __restrict__ s1,
    const float* __restrict__ s2, const float* __restrict__ s3,
    const float* __restrict__ s4,
    _Float16* __restrict__ d0, _Float16* __restrict__ d1,
    _Float16* __restrict__ d2, _Float16* __restrict__ d3,
    _Float16* __restrict__ d4,
    int n0, int n1, int n2, int n3, int n4)
{
    const float* s; _Float16* d; int n;
    switch (blockIdx.y) {
        case 0:  s = s0; d = d0; n = n0; break;
        case 1:  s = s1; d = d1; n = n1; break;
        case 2:  s = s2; d = d2; n = n2; break;
        case 3:  s = s3; d = d3; n = n3; break;
        default: s = s4; d = d4; n = n4; break;
    }
    int i = (blockIdx.x * 256 + threadIdx.x) * 4;
    if (i >= n) return;
    float4 f = *(const float4*)(s + i);
    v4h o = { (_Float16)f.x, (_Float16)f.y, (_Float16)f.z, (_Float16)f.w };
    *(v4h*)(d + i) = o;
}

// ---------------- shared GEMM core: C = A * W^T + bias ----------------
// TM x 128 tile, BK=64, 256 threads (4 waves). XOR-swizzled LDS (16B chunk c of
// row r holds logical chunk c ^ (r&7)); staged via global_load_lds 16B/lane.
// Epilogue via per-wave LDS scratch -> coalesced stores.
// Single-buffered staging: rounds 7 (dbuf) and 8 (TN=64, 4 blocks/CU) were both
// neutral-to-worse — this structure's ~2 blocks/CU implicit cross-block overlap
// already covers the staging latency (cf. learn_hip m99/m100).
// MODE 0: fp16 (B,H,S,D).
// MODE 1: fp16 transposed (B,H,D,S) with PER-64-BLOCK k-permutation
//         p(k) = ((k>>2)&3)*8 + ((k>>4)&1)*4 + (k&3) + 32*(k>>5), so the attention
//         kernel's PV V-fragment is a contiguous conflict-free b128 read.
// MODE 2: fp32 (M,N), TM=64 (wave tile 64x32).
template<int TM, int MODE>
__device__ __forceinline__ void gemm_core(const _Float16* __restrict__ A,
                                          const _Float16* __restrict__ W,
                                          const float* __restrict__ bias,
                                          void* __restrict__ outp,
                                          int row0, int col0)
{
    constexpr int WCOLS = (TM == 128) ? 64 : 32;
    constexpr int NJ = WCOLS / 16;
    constexpr int SC_H = (MODE == 2) ? 4096 : 64 * WCOLS;  // per-wave scratch (halves)
    constexpr int STG_H = (TM + 128) * 64;
    constexpr int TOT_H = (STG_H > 4 * SC_H) ? STG_H : 4 * SC_H;
    __shared__ __align__(16) _Float16 smem[TOT_H];
    _Float16* As = smem;
    _Float16* Bs = smem + TM * 64;

    const int tid  = threadIdx.x;
    const int wave = tid >> 6, lane = tid & 63;
    const int quad = lane >> 4, n16 = lane & 15;
    const int wm = (TM == 128) ? (wave >> 1) : 0;
    const int wn = (TM == 128) ? (wave & 1) : wave;
    const int rL = lane >> 3, c8 = lane & 7;
    const int lcs = c8 ^ rL;

    v4f acc[4][NJ] = {};

    for (int kb = 0; kb < 1024; kb += 64) {
        __syncthreads();
        #pragma unroll
        for (int p = 0; p < TM / 32; p++) {
            int rg = wave * (TM / 32) + p;
            int row = rg * 8 + rL;
            async_copy16(A + (size_t)(row0 + row) * 1024 + kb + lcs * 8, &As[rg * 512]);
        }
        #pragma unroll
        for (int p = 0; p < 4; p++) {
            int rg = wave * 4 + p;
            int row = rg * 8 + rL;
            async_copy16(W + (size_t)(col0 + row) * 1024 + kb + lcs * 8, &Bs[rg * 512]);
        }
        __syncthreads();
        #pragma unroll
        for (int ks = 0; ks < 64; ks += 32) {
            const int pc = ((ks >> 3) + quad) ^ (n16 & 7);
            v8h af[4], bf[NJ];
            #pragma unroll
            for (int i = 0; i < 4; i++)
                af[i] = *(const v8h*)(&As[(wm * 64 + i * 16 + n16) * 64 + pc * 8]);
            #pragma unroll
            for (int j = 0; j < NJ; j++)
                bf[j] = *(const v8h*)(&Bs[(wn * WCOLS + j * 16 + n16) * 64 + pc * 8]);
            #pragma unroll
            for (int i = 0; i < 4; i++)
                #pragma unroll
                for (int j = 0; j < NJ; j++)
                    acc[i][j] = MFMA_F16(af[i], bf[j], acc[i][j]);
        }
    }

    __syncthreads();                       // staged tiles dead; reuse LDS as scratch
    const int b     = (row0 + wm * 64) >> 10;
    const int srow0 = (row0 + wm * 64) & 1023;
    const int C0    = col0 + wn * WCOLS;

    if (MODE == 0) {                       // [s][d] scratch, coalesced (B,H,S,D) stores
        _Float16* sc = smem + wave * SC_H;
        #pragma unroll
        for (int i = 0; i < 4; i++)
            #pragma unroll
            for (int j = 0; j < NJ; j++)
                #pragma unroll
                for (int r = 0; r < 4; r++) {
                    int rowL = i * 16 + quad * 4 + r, colL = j * 16 + n16;
                    float v = acc[i][j][r] + bias[C0 + colL];
                    sc[rowL * 64 + (((colL >> 3) ^ (rowL & 7)) << 3) + (colL & 7)] = (_Float16)v;
                }
        int h = C0 >> 6;
        #pragma unroll
        for (int it = 0; it < 8; it++) {
            int rowR = it * 8 + (lane >> 3), cR = lane & 7;
            v8h val = *(const v8h*)(&sc[rowR * 64 + ((cR ^ (rowR & 7)) << 3)]);
            *(v8h*)((_Float16*)outp +
                    (((size_t)(b * 16 + h) * 1024 + srow0 + rowR) << 6) + cR * 8) = val;
        }
    } else if (MODE == 1) {                // [d][s] scratch, permuted (B,H,D,S) stores
        _Float16* sc = smem + wave * SC_H;
        #pragma unroll
        for (int i = 0; i < 4; i++)
            #pragma unroll
            for (int j = 0; j < NJ; j++) {
                int colL = j * 16 + n16;
                int c16 = i * 2 + (quad >> 1);
                v4h pk;
                #pragma unroll
                for (int r = 0; r < 4; r++)
                    pk[r] = (_Float16)(acc[i][j][r] + bias[C0 + colL]);
                *(v4h*)(&sc[colL * 64 + ((c16 ^ (colL & 7)) << 3) + (quad & 1) * 4]) = pk;
            }
        #pragma unroll
        for (int it = 0; it < 8; it++) {
            int dR = it * 8 + (lane >> 3), g = lane & 7;
            v8h val = *(const v8h*)(&sc[dR * 64 + ((g ^ (dR & 7)) << 3)]);
            int cg = C0 + dR;
            int h = cg >> 6, dl = cg & 63;
            _Float16* base = (_Float16*)outp +
                             ((size_t)((b * 16 + h) * 64 + dl) << 10) + srow0;
            // k-block permutation: original s-cols [8g..8g+7] scatter as two v4h
            int a4  = ((g >> 1) & 1) * 4, b32 = (g >> 2) * 32;
            int p0  = b32 + ((2 * g) & 3) * 8 + a4;
            int p1  = b32 + ((2 * g + 1) & 3) * 8 + a4;
            v4h lo = __builtin_shufflevector(val, val, 0, 1, 2, 3);
            v4h hi = __builtin_shufflevector(val, val, 4, 5, 6, 7);
            *(v4h*)(base + p0) = lo;
            *(v4h*)(base + p1) = hi;
        }
    } else {                               // MODE 2 (TM=64): fp32 [m][n], wave tile 64x32
        float* sc = (float*)smem + wave * 2048;
        #pragma unroll
        for (int i = 0; i < 4; i++)
            #pragma unroll
            for (int j = 0; j < 2; j++)
                #pragma unroll
                for (int r = 0; r < 4; r++) {
                    int rowL = i * 16 + quad * 4 + r, colL = j * 16 + n16;
                    sc[rowL * 32 + (((colL >> 2) ^ (rowL & 7)) << 2) + (colL & 3)] =
                        acc[i][j][r] + bias[col0 + wn * 32 + colL];
                }
        #pragma unroll
        for (int it = 0; it < 8; it++) {
            int rowR = it * 8 + (lane >> 3), cR = lane & 7;
            v4f val = *(const v4f*)(&sc[rowR * 32 + ((cR ^ (rowR & 7)) << 2)]);
            *(v4f*)((float*)outp + (size_t)(row0 + rowR) * 1024 + col0 + wn * 32 + cR * 4) = val;
        }
    }
}

// 512 blocks, TM=128. XCD swizzle keyed on A row-strip.
__global__ __launch_bounds__(256) void gemm_qv_kernel(
    const _Float16* __restrict__ Aq, const _Float16* __restrict__ Av,
    const _Float16* __restrict__ Wq, const _Float16* __restrict__ Wv,
    const float* __restrict__ bq, const float* __restrict__ bv,
    _Float16* __restrict__ q_out, _Float16* __restrict__ v_out)
{
    int id = blockIdx.x;
    int y = (id & 7) | (((id >> 3) & 3) << 3);   // 0..31
    int x = (id >> 5) & 7;                       // 0..7
    int z = id >> 8;                             // 0..1
    if (z) gemm_core<128, 1>(Av, Wv, bv, (void*)v_out, y * 128, x * 128);
    else   gemm_core<128, 0>(Aq, Wq, bq, (void*)q_out, y * 128, x * 128);
}

// 512 blocks, TM=64, fp32 output.
__global__ __launch_bounds__(256) void gemm_o_kernel(
    const _Float16* __restrict__ A, const _Float16* __restrict__ W,
    const float* __restrict__ bias, float* __restrict__ outp)
{
    int id = blockIdx.x;
    int y = (id & 7) * 8 + ((id >> 3) & 7);      // 0..63
    int x = id >> 6;                             // 0..7
    gemm_core<64, 2>(A, W, bias, (void*)outp, y * 64, x * 128);
}

// ---------------- fused attention (S^T, static-max softmax, K == Q) -------------
// Block: 64 q-rows (4 waves x 16). 1-D grid: bh = blk&63 (XCD-local), qtile = blk>>6.
// Round-4 structure (best measured: attn 40.9us, total 195.5us): software-pipelined
// scores. During iter it the wave computes s_next = QK(K[it+1]) — MFMAs fully
// independent of the exp/pack phase on s_cur — so the SIMD co-schedules them
// instead of serializing QK -> exp -> PV. K[it] is dead during iter it (consumed
// last iter), so K[it+2] stages into its buffer: 2 K buffers suffice. V is
// single-buffered: staged at iter top, drained by the mid-iter barrier after
// QK-ahead+exp (latency hidden under them). LDS 25.9KB. Occupancy is grid-limited
// at 4 blocks/CU (1024 blocks / 256 CU). launch_bounds(256,4): VGPR cap 128 —
// never cap below live state (round 3's (256,8) forced 1.3GB of scratch traffic;
// round 5's V-register hoist spilled at the same cap).
// Keeps: exp2-folded softmax, |dqt|>=17 fast paths, tree buckets, no setprio.
__global__ __launch_bounds__(256, 4) void attn_kernel(
    const _Float16* __restrict__ qb,   // (B,H,S,D) fp16
    const _Float16* __restrict__ vt,   // (B,H,D,S) fp16, k-permuted per 64-block
    const float* __restrict__ rpk, const float* __restrict__ rpv,  // (5,64) fp32
    _Float16* __restrict__ attn_o)     // (B*S, H*D) fp16
{
    const int blk = blockIdx.x;
    const int bh = blk & 63;
    const int q0 = (blk >> 6) * 64;
    const int tid = threadIdx.x;
    const int wave = tid >> 6, lane = tid & 63;
    const int quad = lane >> 4, n16 = lane & 15;
    const int qw = q0 + wave * 16;
    const _Float16* Qh = qb + (size_t)bh * 1024 * 64;
    const _Float16* Vh = vt + (size_t)bh * 64 * 1024;

    __shared__ __align__(16) _Float16 Ks[2][64 * 64];
    __shared__ __align__(16) _Float16 Vs[64 * 64];
    __shared__ float rqs[4][16][5];

    const int rL = lane >> 3, c8 = lane & 7;
    const int lcs = c8 ^ rL;

    // prologue: stage K[0] and K[1] (K tile j lives in Ks[j&1])
    #pragma unroll
    for (int p = 0; p < 2; p++) {
        int c = wave * 2 + p;
        int row = c * 8 + rL;
        async_copy16(Qh + (size_t)row * 64 + lcs * 8, &Ks[0][c * 512]);
        async_copy16(Qh + (size_t)(64 + row) * 64 + lcs * 8, &Ks[1][c * 512]);
    }

    // rc[t] = (dot(q_row, rpk[t]) - |q_row|^2) * 0.125 * log2e  (exp2-folded)
    {
        int m = lane >> 2, seg = lane & 3;
        const _Float16* qrow = Qh + (size_t)(qw + m) * 64 + seg * 16;
        v8h qa = *(const v8h*)(qrow);
        v8h qc = *(const v8h*)(qrow + 8);
        float qd[16];
        #pragma unroll
        for (int x = 0; x < 8; x++) { qd[x] = (float)qa[x]; qd[8 + x] = (float)qc[x]; }
        float qq = 0.f;
        #pragma unroll
        for (int x = 0; x < 16; x++) qq += qd[x] * qd[x];
        qq += __shfl_xor(qq, 1);
        qq += __shfl_xor(qq, 2);
        #pragma unroll
        for (int t = 0; t < 5; t++) {
            float s = 0.f;
            #pragma unroll
            for (int x = 0; x < 16; x++) s += qd[x] * rpk[t * 64 + seg * 16 + x];
            s += __shfl_xor(s, 1);
            s += __shfl_xor(s, 2);
            if (seg == 0) rqs[wave][m][t] = (s - qq) * 0.18033688736f;
        }
    }

    // Q fragment (B-operand): B[n=q=lane&15][k=quad*8+j]
    v8h aq0 = *(const v8h*)(Qh + (size_t)(qw + n16) * 64 + quad * 8);
    v8h aq1 = *(const v8h*)(Qh + (size_t)(qw + n16) * 64 + 32 + quad * 8);

    __syncthreads();   // K[0], K[1] resident; rqs visible

    float rc[5];
    #pragma unroll
    for (int t = 0; t < 5; t++) rc[t] = rqs[wave][n16][t];

    const int pphys0 = quad ^ (n16 & 7);
    const int pphys1 = (quad + 4) ^ (n16 & 7);
    const float SCL = 0.18033688736f;      // 0.125 * log2(e)

    // pipeline prime: s_cur = QK(K[0])
    v4f scur[4];
    #pragma unroll
    for (int t = 0; t < 4; t++) {
        v8h k0 = *(const v8h*)(&Ks[0][(t * 16 + n16) * 64 + pphys0 * 8]);
        v8h k1 = *(const v8h*)(&Ks[0][(t * 16 + n16) * 64 + pphys1 * 8]);
        v4f s = {0.f, 0.f, 0.f, 0.f};
        s = MFMA_F16(k0, aq0, s);
        scur[t] = MFMA_F16(k1, aq1, s);
    }
    __syncthreads();   // all waves done reading Ks[0] before iter 0 stages K[2] into it

    // bucket sums for this lane's q-row (index = rpk/rpv table row):
    // 4: diff>=2, 3: diff==1, 2: diff==0, 1: diff==-1, 0: diff<=-2
    float bkt[5] = {0.f, 0.f, 0.f, 0.f, 0.f};
    v4f O[4] = {};

    for (int it = 0; it < 16; ++it) {
        const int kb = it * 64;

        // 1. stage V[it] into Vs (freed by the barrier that ended iter it-1)
        #pragma unroll
        for (int p = 0; p < 2; p++) {
            int c = wave * 2 + p;
            int row = c * 8 + rL;
            async_copy16(Vh + (size_t)row * 1024 + kb + lcs * 8, &Vs[c * 512]);
        }
        // 2. stage K[it+2] into the dead buffer Ks[it&1]
        if (it + 2 < 16) {
            const int kn = kb + 128;
            #pragma unroll
            for (int p = 0; p < 2; p++) {
                int c = wave * 2 + p;
                int row = c * 8 + rL;
                async_copy16(Qh + (size_t)(kn + row) * 64 + lcs * 8, &Ks[it & 1][c * 512]);
            }
        }

        // 3. QK-ahead: s_next = QK(K[it+1]) from Ks[(it+1)&1] — independent of the
        //    exp phase below; the scheduler interleaves MFMA issue with VALU/trans.
        v4f snx[4] = {};
        if (it + 1 < 16) {
            #pragma unroll
            for (int t = 0; t < 4; t++) {
                v8h k0 = *(const v8h*)(&Ks[(it + 1) & 1][(t * 16 + n16) * 64 + pphys0 * 8]);
                v8h k1 = *(const v8h*)(&Ks[(it + 1) & 1][(t * 16 + n16) * 64 + pphys1 * 8]);
                v4f s = {0.f, 0.f, 0.f, 0.f};
                s = MFMA_F16(k0, aq0, s);
                snx[t] = MFMA_F16(k1, aq1, s);
            }
        }

        // 4. exp/pack on s_cur: lane owns q = qw+n16, k = t*16 + quad*4 + r
        int pkLo[4], pkHi[4];
        #pragma unroll
        for (int t = 0; t < 4; t++) {
            const v4f s = scur[t];
            const int dqt = qw - kb - t * 16;      // wave-uniform
            float pv[4];
            if (dqt >= 17) {                       // whole tile diff >= 2
                float p0 = exp2_hw(fmaf(s[0], SCL, rc[4]));
                float p1 = exp2_hw(fmaf(s[1], SCL, rc[4]));
                float p2 = exp2_hw(fmaf(s[2], SCL, rc[4]));
                float p3 = exp2_hw(fmaf(s[3], SCL, rc[4]));
                pv[0] = p0; pv[1] = p1; pv[2] = p2; pv[3] = p3;
                bkt[4] += (p0 + p1) + (p2 + p3);   // tree: short dep chain
            } else if (dqt <= -17) {               // whole tile diff <= -2
                float p0 = exp2_hw(fmaf(s[0], SCL, rc[0]));
                float p1 = exp2_hw(fmaf(s[1], SCL, rc[0]));
                float p2 = exp2_hw(fmaf(s[2], SCL, rc[0]));
                float p3 = exp2_hw(fmaf(s[3], SCL, rc[0]));
                pv[0] = p0; pv[1] = p1; pv[2] = p2; pv[3] = p3;
                bkt[0] += (p0 + p1) + (p2 + p3);
            } else {                               // near-diagonal tile
                const int D0 = dqt + n16 - quad * 4;
                #pragma unroll
                for (int r = 0; r < 4; r++) {
                    int diff = D0 - r;
                    float rv = diff >= 2  ? rc[4]
                             : diff == 1  ? rc[3]
                             : diff == 0  ? rc[2]
                             : diff == -1 ? rc[1]
                                          : rc[0];
                    float p = exp2_hw(fmaf(s[r], SCL, rv));
                    pv[r] = p;
                    bkt[4] += (diff >= 2)  ? p : 0.f;
                    bkt[3] += (diff == 1)  ? p : 0.f;
                    bkt[2] += (diff == 0)  ? p : 0.f;
                    bkt[1] += (diff == -1) ? p : 0.f;
                    bkt[0] += (diff <= -2) ? p : 0.f;
                }
            }
            pkLo[t] = __builtin_bit_cast(int, __builtin_amdgcn_cvt_pkrtz(pv[0], pv[1]));
            pkHi[t] = __builtin_bit_cast(int, __builtin_amdgcn_cvt_pkrtz(pv[2], pv[3]));
        }

        // 5. barrier B: drains V[it] staging (and K[it+2], needed next iter)
        __syncthreads();

        // 6. PV: P registers ARE the B-operand (k-slot order k = t*16+quad*4+r);
        //    V A-operand is a contiguous conflict-free b128 LDS read.
        union { int d[4]; v8h v; } ub0, ub1;
        ub0.d[0] = pkLo[0]; ub0.d[1] = pkHi[0]; ub0.d[2] = pkLo[1]; ub0.d[3] = pkHi[1];
        ub1.d[0] = pkLo[2]; ub1.d[1] = pkHi[2]; ub1.d[2] = pkLo[3]; ub1.d[3] = pkHi[3];
        v8h bf0 = ub0.v, bf1 = ub1.v;

        #pragma unroll
        for (int dt = 0; dt < 4; dt++) {
            const int rowd = (dt * 16 + n16) * 64;
            v8h av0 = *(const v8h*)(&Vs[rowd + pphys0 * 8]);
            v8h av1 = *(const v8h*)(&Vs[rowd + pphys1 * 8]);
            O[dt] = MFMA_F16(av0, bf0, O[dt]);    // O^T: row = d-local, col = q
            O[dt] = MFMA_F16(av1, bf1, O[dt]);
        }

        // 7. barrier A: Vs free for next iter's staging; Ks[(it+1)&1] free for it+3
        __syncthreads();

        // rotate pipeline registers
        #pragma unroll
        for (int t = 0; t < 4; t++) scur[t] = snx[t];
    }

    // epilogue: reduce buckets across the 4 quads sharing this q-row
    #pragma unroll
    for (int t = 0; t < 5; t++) {
        bkt[t] += __shfl_xor(bkt[t], 16);
        bkt[t] += __shfl_xor(bkt[t], 32);
    }
    float l = bkt[0] + bkt[1] + bkt[2] + bkt[3] + bkt[4];
    float inv = 1.0f / l;
    int q = qw + n16;
    size_t orow = (size_t)((bh >> 4) * 1024 + q) * 1024 + (bh & 15) * 64;
    #pragma unroll
    for (int dt = 0; dt < 4; dt++) {
        int d0 = dt * 16 + quad * 4;
        v4h st;
        #pragma unroll
        for (int r = 0; r < 4; r++) {
            int d = d0 + r;
            float w2 = bkt[4] * rpv[4 * 64 + d] + bkt[3] * rpv[3 * 64 + d]
                     + bkt[2] * rpv[2 * 64 + d] + bkt[1] * rpv[1 * 64 + d]
                     + bkt[0] * rpv[0 * 64 + d];
            st[r] = (_Float16)((O[dt][r] + w2) * inv);
        }
        *(v4h*)(attn_o + orow + d0) = st;
    }
}

// ---------------- host launcher ----------------
extern "C" void kernel_launch(void* const* d_in, const int* in_sizes, int n_in,
                              void* d_out, int out_size, void* d_ws, size_t ws_size,
                              hipStream_t stream)
{
    const float* query = (const float*)d_in[0];
    // d_in[1] = key (unused: reference's k projection is dead code)
    const float* value = (const float*)d_in[2];
    const float* Wq = (const float*)d_in[3];
    const float* bq = (const float*)d_in[4];
    // d_in[5], d_in[6] = Wk, bk (unused)
    const float* Wv = (const float*)d_in[7];
    const float* bv = (const float*)d_in[8];
    const float* Wo = (const float*)d_in[9];
    const float* bo = (const float*)d_in[10];
    const float* rpk = (const float*)d_in[11];
    const float* rpv = (const float*)d_in[12];
    float* out = (float*)d_out;

    char* ws = (char*)d_ws;
    const size_t MB = 1024 * 1024;
    _Float16* q_bhsd = (_Float16*)(ws);             // 8 MB: q proj (B,H,S,D)
    _Float16* v_t    = (_Float16*)(ws + 8 * MB);    // 8 MB: v proj (B,H,D,S) permuted
    _Float16* q16    = (_Float16*)(ws + 16 * MB);   // 8 MB: query fp16
    _Float16* attn_o = (_Float16*)(ws + 16 * MB);   // aliases q16 (dead after gemm_qv)
    _Float16* v16    = (_Float16*)(ws + 24 * MB);   // 8 MB: value fp16
    _Float16* wq16   = (_Float16*)(ws + 32 * MB);   // 2 MB
    _Float16* wv16   = (_Float16*)(ws + 34 * MB);   // 2 MB
    _Float16* wo16   = (_Float16*)(ws + 36 * MB);   // 2 MB   (total 38 MB)

    cvt5_kernel<<<dim3(4096, 5), 256, 0, stream>>>(
        query, value, Wq, Wv, Wo, q16, v16, wq16, wv16, wo16,
        4096 * 1024, 4096 * 1024, 1024 * 1024, 1024 * 1024, 1024 * 1024);

    gemm_qv_kernel<<<dim3(512), 256, 0, stream>>>(
        q16, v16, wq16, wv16, bq, bv, q_bhsd, v_t);

    attn_kernel<<<dim3(1024), 256, 0, stream>>>(q_bhsd, v_t, rpk, rpv, attn_o);

    gemm_o_kernel<<<dim3(512), 256, 0, stream>>>(attn_o, wo16, bo, out);
}